// Round 1
// baseline (3091.921 us; speedup 1.0000x reference)
//
#include <hip/hip_runtime.h>
#include <stdint.h>

typedef __attribute__((ext_vector_type(4))) float floatx4;
typedef __attribute__((ext_vector_type(8))) short short8;

// Problem constants
#define BB 16
#define SS 512
#define DD 2048
#define HH_ 16
#define HD 128
#define GG 4
#define MM (BB*SS)          // 8192
#define NQKV 3072           // 2048 q + 512 k + 512 v

__device__ __forceinline__ unsigned short f2bf(float f){
  unsigned u = __builtin_bit_cast(unsigned, f);
  u += 0x7fffu + ((u >> 16) & 1u);            // RNE
  return (unsigned short)(u >> 16);
}
__device__ __forceinline__ float bf2f_lo(unsigned d){  // low bf16 of a packed dword
  return __builtin_bit_cast(float, d << 16);
}
__device__ __forceinline__ float bf2f_hi(unsigned d){  // high bf16
  return __builtin_bit_cast(float, d & 0xffff0000u);
}

__device__ __forceinline__ void async_copy16(const void* g, void* l){
  __builtin_amdgcn_global_load_lds((const __attribute__((address_space(1))) unsigned*)g,
                                   (__attribute__((address_space(3))) unsigned*)l,
                                   16, 0, 0);
}

// ---------------- fp32 -> bf16 elementwise convert (x) ----------------
__global__ __launch_bounds__(256) void cvt_x_kernel(const float* __restrict__ src,
                                                    unsigned short* __restrict__ dst, int n4){
  int i = blockIdx.x * 256 + threadIdx.x;
  if (i >= n4) return;
  float4 f = ((const float4*)src)[i];
  ushort4 o;
  o.x = f2bf(f.x); o.y = f2bf(f.y); o.z = f2bf(f.z); o.w = f2bf(f.w);
  ((ushort4*)dst)[i] = o;
}

// ---------------- fp32 (R x C) -> bf16 transpose (C x R) ----------------
__global__ void tr_cvt_kernel(const float* __restrict__ src, unsigned short* __restrict__ dst,
                              int R, int C){
  __shared__ float tile[32][33];
  int c0 = blockIdx.x * 32, r0 = blockIdx.y * 32;
  int tx = threadIdx.x, ty = threadIdx.y;
  #pragma unroll
  for (int j = 0; j < 32; j += 8)
    tile[ty + j][tx] = src[(size_t)(r0 + ty + j) * C + (c0 + tx)];
  __syncthreads();
  #pragma unroll
  for (int j = 0; j < 32; j += 8)
    dst[(size_t)(c0 + ty + j) * R + (r0 + tx)] = f2bf(tile[tx][ty + j]);
}

// ---------------- concat bias [bq | bk | bv] ----------------
__global__ void bias_cat_kernel(const float* __restrict__ bq, const float* __restrict__ bk,
                                const float* __restrict__ bv, float* __restrict__ out){
  int i = blockIdx.x * 256 + threadIdx.x;
  if (i >= NQKV) return;
  out[i] = (i < 2048) ? bq[i] : (i < 2560 ? bk[i - 2048] : bv[i - 2560]);
}

// ---------------- bf16 GEMM: C = A(MxK) @ Bt(NxK)^T + bias ----------------
// m97-style: 128x128 tile, BK=32, global_load_lds(16B), 4 waves each 4x4 16x16x32 MFMAs
template<bool OUT_BF16>
__global__ __launch_bounds__(256) void gemm_bt_kernel(
    const unsigned short* __restrict__ A,
    const unsigned short* __restrict__ Bt,
    void* __restrict__ Cout,
    const float* __restrict__ bias,
    int M, int N, int K, int ldc)
{
  __shared__ unsigned short sA[128 * 32];   // 8 KB
  __shared__ unsigned short sB[128 * 32];   // 8 KB
  const int tid  = threadIdx.x;
  const int wave = tid >> 6;
  const int lane = tid & 63;
  const int m0 = blockIdx.y * 128;
  const int n0 = blockIdx.x * 128;
  const int wm = (wave >> 1) * 64;
  const int wn = (wave & 1) * 64;

  floatx4 acc[4][4];
  #pragma unroll
  for (int i = 0; i < 4; i++)
    #pragma unroll
    for (int j = 0; j < 4; j++)
      acc[i][j] = (floatx4){0.f, 0.f, 0.f, 0.f};

  // staging: wave w fills LDS rows [32w, 32w+32), two 1KB calls of 16 rows each
  const int rA = 32 * wave + (lane >> 2);
  const int cH = (lane & 3) * 8;                       // ushort offset in 32-wide row
  const unsigned short* gA0 = A  + (size_t)(m0 + rA)      * K + cH;
  const unsigned short* gA1 = A  + (size_t)(m0 + rA + 16) * K + cH;
  const unsigned short* gB0 = Bt + (size_t)(n0 + rA)      * K + cH;
  const unsigned short* gB1 = Bt + (size_t)(n0 + rA + 16) * K + cH;
  unsigned short* lA0 = &sA[wave * 1024];
  unsigned short* lA1 = &sA[wave * 1024 + 512];
  unsigned short* lB0 = &sB[wave * 1024];
  unsigned short* lB1 = &sB[wave * 1024 + 512];

  const int fOffBase = (lane & 15) * 32 + (lane >> 4) * 8;

  for (int k0 = 0; k0 < K; k0 += 32) {
    async_copy16(gA0 + k0, lA0);
    async_copy16(gA1 + k0, lA1);
    async_copy16(gB0 + k0, lB0);
    async_copy16(gB1 + k0, lB1);
    __syncthreads();

    short8 aF[4], bF[4];
    #pragma unroll
    for (int i = 0; i < 4; i++)
      aF[i] = *(const short8*)(&sA[(wm + i * 16) * 32 + fOffBase]);
    #pragma unroll
    for (int j = 0; j < 4; j++)
      bF[j] = *(const short8*)(&sB[(wn + j * 16) * 32 + fOffBase]);

    #pragma unroll
    for (int i = 0; i < 4; i++)
      #pragma unroll
      for (int j = 0; j < 4; j++)
        acc[i][j] = __builtin_amdgcn_mfma_f32_16x16x32_bf16(aF[i], bF[j], acc[i][j], 0, 0, 0);
    __syncthreads();
  }

  // epilogue: C/D layout col = lane&15, row = (lane>>4)*4 + reg
  const int cr = (lane >> 4) * 4;
  const int cc = lane & 15;
  #pragma unroll
  for (int j = 0; j < 4; j++) {
    const int col = n0 + wn + j * 16 + cc;
    const float bval = bias[col];
    #pragma unroll
    for (int i = 0; i < 4; i++) {
      #pragma unroll
      for (int r = 0; r < 4; r++) {
        const int row = m0 + wm + i * 16 + cr + r;
        const float v = acc[i][j][r] + bval;
        if (OUT_BF16)
          ((unsigned short*)Cout)[(size_t)row * ldc + col] = f2bf(v);
        else
          ((float*)Cout)[(size_t)row * ldc + col] = v;
      }
    }
  }
}

// ---------------- fused RMSNorm + RoPE on q,k heads of qkv buffer ----------------
// one wave per (row, head); lane l holds interleaved pair (2l, 2l+1)
__global__ __launch_bounds__(256) void norm_rope_kernel(
    unsigned short* __restrict__ qkv,
    const float* __restrict__ qs, const float* __restrict__ ks)
{
  const int wave = threadIdx.x >> 6, lane = threadIdx.x & 63;
  const int gw  = blockIdx.x * 4 + wave;
  const int row = gw / 20;          // 8192 rows
  const int hh  = gw % 20;          // 0..15 q heads, 16..19 k heads
  const bool isq = hh < 16;

  unsigned* p = (unsigned*)(qkv + (size_t)row * NQKV + hh * 128) + lane;
  unsigned d = *p;
  float x1 = bf2f_lo(d), x2 = bf2f_hi(d);

  float ss = x1 * x1 + x2 * x2;
  #pragma unroll
  for (int off = 32; off; off >>= 1) ss += __shfl_xor(ss, off, 64);
  const float r = rsqrtf(ss * (1.f / 128.f) + 1e-6f);

  const float2 sc = ((const float2*)(isq ? qs : ks))[lane];
  float n1 = x1 * r * sc.x;
  float n2 = x2 * r * sc.y;

  // RoPE: freq_i = 10000^(-2i/128), i = lane; t = row % 512
  const float t = (float)(row & (SS - 1));
  const float freq = __expf((float)lane * (-2.f / 128.f) * 9.21034037197618f); // ln(10000)
  float sn, cs;
  __sincosf(t * freq, &sn, &cs);
  float o1 = n1 * cs - n2 * sn;
  float o2 = n1 * sn + n2 * cs;
  if (isq) { o1 *= (1.f / 128.f); o2 *= (1.f / 128.f); }  // both inv_sqrt_hd factors

  *p = (unsigned)f2bf(o1) | ((unsigned)f2bf(o2) << 16);
}

// ---------------- attention: one wave per (b, h, s_q), fp32 online softmax ----------------
__global__ __launch_bounds__(256) void attn_kernel(
    const unsigned short* __restrict__ qkv,
    unsigned short* __restrict__ aout)
{
  const int wave = threadIdx.x >> 6, lane = threadIdx.x & 63;
  const int gw = blockIdx.x * 4 + wave;
  const int sq = gw & (SS - 1);
  const int bh = gw >> 9;
  const int b = bh >> 4, h = bh & 15;
  const int g = h >> 2;               // 4 q-heads per kv group

  const unsigned* qp = (const unsigned*)(qkv + ((size_t)(b * SS + sq)) * NQKV + h * 128) + lane;
  const unsigned qd = *qp;
  const float q1 = bf2f_lo(qd), q2 = bf2f_hi(qd);

  const unsigned short* kbase = qkv + (size_t)b * SS * NQKV + 2048 + g * 128;
  float m = -INFINITY, l = 0.f, o1 = 0.f, o2 = 0.f;

  for (int t = 0; t <= sq; ++t) {
    const unsigned kd = *((const unsigned*)(kbase + (size_t)t * NQKV) + lane);
    float s = q1 * bf2f_lo(kd) + q2 * bf2f_hi(kd);
    #pragma unroll
    for (int off = 32; off; off >>= 1) s += __shfl_xor(s, off, 64);
    const unsigned vd = *((const unsigned*)(kbase + 512 + (size_t)t * NQKV) + lane);
    const float mn = fmaxf(m, s);
    const float al = __expf(m - mn);
    const float pp = __expf(s - mn);
    l  = l  * al + pp;
    o1 = o1 * al + pp * bf2f_lo(vd);
    o2 = o2 * al + pp * bf2f_hi(vd);
    m = mn;
  }
  const float inv = 1.f / l;
  unsigned* op = (unsigned*)(aout + ((size_t)(b * SS + sq)) * DD + h * 128) + lane;
  *op = (unsigned)f2bf(o1 * inv) | ((unsigned)f2bf(o2 * inv) << 16);
}

extern "C" void kernel_launch(void* const* d_in, const int* in_sizes, int n_in,
                              void* d_out, int out_size, void* d_ws, size_t ws_size,
                              hipStream_t stream) {
  const float* x   = (const float*)d_in[0];
  const float* Wq  = (const float*)d_in[1];
  const float* bq  = (const float*)d_in[2];
  const float* Wk  = (const float*)d_in[3];
  const float* bk  = (const float*)d_in[4];
  const float* Wv  = (const float*)d_in[5];
  const float* bv  = (const float*)d_in[6];
  const float* Wo  = (const float*)d_in[7];
  const float* bo  = (const float*)d_in[8];
  const float* qns = (const float*)d_in[9];
  const float* kns = (const float*)d_in[10];

  char* ws = (char*)d_ws;
  unsigned short* xb    = (unsigned short*)(ws);                 // 8192x2048 bf16 = 33,554,432
  unsigned short* WqkvT = (unsigned short*)(ws + 33554432);      // 3072x2048 bf16 = 12,582,912
  unsigned short* WoT   = (unsigned short*)(ws + 46137344);      // 2048x2048 bf16 =  8,388,608
  float*          bqkv  = (float*)         (ws + 54525952);      // 3072 f32       =     12,288
  unsigned short* qkv   = (unsigned short*)(ws + 54538240);      // 8192x3072 bf16 = 50,331,648
  unsigned short* aout  = (unsigned short*)(ws + 104869888);     // 8192x2048 bf16 = 33,554,432
  // total 138,424,320 bytes

  dim3 tb(32, 8);
  cvt_x_kernel<<<16384, 256, 0, stream>>>(x, xb, MM * DD / 4);
  tr_cvt_kernel<<<dim3(64, 64), tb, 0, stream>>>(Wq, WqkvT, 2048, 2048);
  tr_cvt_kernel<<<dim3(16, 64), tb, 0, stream>>>(Wk, WqkvT + (size_t)2048 * 2048, 2048, 512);
  tr_cvt_kernel<<<dim3(16, 64), tb, 0, stream>>>(Wv, WqkvT + (size_t)2560 * 2048, 2048, 512);
  tr_cvt_kernel<<<dim3(64, 64), tb, 0, stream>>>(Wo, WoT, 2048, 2048);
  bias_cat_kernel<<<12, 256, 0, stream>>>(bq, bk, bv, bqkv);

  // fused QKV projection: (8192x2048) @ (2048x3072) -> qkv bf16
  gemm_bt_kernel<true><<<dim3(24, 64), 256, 0, stream>>>(xb, WqkvT, qkv, bqkv,
                                                         MM, NQKV, DD, NQKV);
  // rmsnorm + rope on q (16 heads) and k (4 heads) per row
  norm_rope_kernel<<<40960, 256, 0, stream>>>(qkv, qns, kns);
  // attention
  attn_kernel<<<32768, 256, 0, stream>>>(qkv, aout);
  // output projection -> fp32 d_out
  gemm_bt_kernel<false><<<dim3(16, 64), 256, 0, stream>>>(aout, WoT, d_out, bo,
                                                          MM, DD, DD, DD);
  (void)in_sizes; (void)n_in; (void)out_size; (void)ws_size;
}

// Round 2
// 488.526 us; speedup vs baseline: 6.3291x; 6.3291x over previous
//
#include <hip/hip_runtime.h>
#include <stdint.h>

typedef __attribute__((ext_vector_type(4))) float floatx4;
typedef __attribute__((ext_vector_type(8))) short short8;

// Problem constants
#define BB 16
#define SS 512
#define DD 2048
#define HH_ 16
#define HD 128
#define GG 4
#define MM (BB*SS)          // 8192
#define NQKV 3072           // 2048 q + 512 k + 512 v

__device__ __forceinline__ unsigned short f2bf(float f){
  unsigned u = __builtin_bit_cast(unsigned, f);
  u += 0x7fffu + ((u >> 16) & 1u);            // RNE
  return (unsigned short)(u >> 16);
}
__device__ __forceinline__ float bf2f_lo(unsigned d){  // low bf16 of a packed dword
  return __builtin_bit_cast(float, d << 16);
}
__device__ __forceinline__ float bf2f_hi(unsigned d){  // high bf16
  return __builtin_bit_cast(float, d & 0xffff0000u);
}

__device__ __forceinline__ void async_copy16(const void* g, void* l){
  __builtin_amdgcn_global_load_lds((const __attribute__((address_space(1))) unsigned*)g,
                                   (__attribute__((address_space(3))) unsigned*)l,
                                   16, 0, 0);
}

// ---------------- fp32 -> bf16 elementwise convert (x) ----------------
__global__ __launch_bounds__(256) void cvt_x_kernel(const float* __restrict__ src,
                                                    unsigned short* __restrict__ dst, int n4){
  int i = blockIdx.x * 256 + threadIdx.x;
  if (i >= n4) return;
  float4 f = ((const float4*)src)[i];
  ushort4 o;
  o.x = f2bf(f.x); o.y = f2bf(f.y); o.z = f2bf(f.z); o.w = f2bf(f.w);
  ((ushort4*)dst)[i] = o;
}

// ---------------- fp32 (R x C) -> bf16 transpose (C x R) ----------------
__global__ void tr_cvt_kernel(const float* __restrict__ src, unsigned short* __restrict__ dst,
                              int R, int C){
  __shared__ float tile[32][33];
  int c0 = blockIdx.x * 32, r0 = blockIdx.y * 32;
  int tx = threadIdx.x, ty = threadIdx.y;
  #pragma unroll
  for (int j = 0; j < 32; j += 8)
    tile[ty + j][tx] = src[(size_t)(r0 + ty + j) * C + (c0 + tx)];
  __syncthreads();
  #pragma unroll
  for (int j = 0; j < 32; j += 8)
    dst[(size_t)(c0 + ty + j) * R + (r0 + tx)] = f2bf(tile[tx][ty + j]);
}

// ---------------- concat bias [bq | bk | bv] ----------------
__global__ void bias_cat_kernel(const float* __restrict__ bq, const float* __restrict__ bk,
                                const float* __restrict__ bv, float* __restrict__ out){
  int i = blockIdx.x * 256 + threadIdx.x;
  if (i >= NQKV) return;
  out[i] = (i < 2048) ? bq[i] : (i < 2560 ? bk[i - 2048] : bv[i - 2560]);
}

// ---------------- bf16 GEMM: C = A(MxK) @ Bt(NxK)^T + bias ----------------
template<bool OUT_BF16>
__global__ __launch_bounds__(256) void gemm_bt_kernel(
    const unsigned short* __restrict__ A,
    const unsigned short* __restrict__ Bt,
    void* __restrict__ Cout,
    const float* __restrict__ bias,
    int M, int N, int K, int ldc)
{
  __shared__ unsigned short sA[128 * 32];   // 8 KB
  __shared__ unsigned short sB[128 * 32];   // 8 KB
  const int tid  = threadIdx.x;
  const int wave = tid >> 6;
  const int lane = tid & 63;
  const int m0 = blockIdx.y * 128;
  const int n0 = blockIdx.x * 128;
  const int wm = (wave >> 1) * 64;
  const int wn = (wave & 1) * 64;

  floatx4 acc[4][4];
  #pragma unroll
  for (int i = 0; i < 4; i++)
    #pragma unroll
    for (int j = 0; j < 4; j++)
      acc[i][j] = (floatx4){0.f, 0.f, 0.f, 0.f};

  const int rA = 32 * wave + (lane >> 2);
  const int cH = (lane & 3) * 8;
  const unsigned short* gA0 = A  + (size_t)(m0 + rA)      * K + cH;
  const unsigned short* gA1 = A  + (size_t)(m0 + rA + 16) * K + cH;
  const unsigned short* gB0 = Bt + (size_t)(n0 + rA)      * K + cH;
  const unsigned short* gB1 = Bt + (size_t)(n0 + rA + 16) * K + cH;
  unsigned short* lA0 = &sA[wave * 1024];
  unsigned short* lA1 = &sA[wave * 1024 + 512];
  unsigned short* lB0 = &sB[wave * 1024];
  unsigned short* lB1 = &sB[wave * 1024 + 512];

  const int fOffBase = (lane & 15) * 32 + (lane >> 4) * 8;

  for (int k0 = 0; k0 < K; k0 += 32) {
    async_copy16(gA0 + k0, lA0);
    async_copy16(gA1 + k0, lA1);
    async_copy16(gB0 + k0, lB0);
    async_copy16(gB1 + k0, lB1);
    __syncthreads();

    short8 aF[4], bF[4];
    #pragma unroll
    for (int i = 0; i < 4; i++)
      aF[i] = *(const short8*)(&sA[(wm + i * 16) * 32 + fOffBase]);
    #pragma unroll
    for (int j = 0; j < 4; j++)
      bF[j] = *(const short8*)(&sB[(wn + j * 16) * 32 + fOffBase]);

    #pragma unroll
    for (int i = 0; i < 4; i++)
      #pragma unroll
      for (int j = 0; j < 4; j++)
        acc[i][j] = __builtin_amdgcn_mfma_f32_16x16x32_bf16(aF[i], bF[j], acc[i][j], 0, 0, 0);
    __syncthreads();
  }

  const int cr = (lane >> 4) * 4;
  const int cc = lane & 15;
  #pragma unroll
  for (int j = 0; j < 4; j++) {
    const int col = n0 + wn + j * 16 + cc;
    const float bval = bias[col];
    #pragma unroll
    for (int i = 0; i < 4; i++) {
      #pragma unroll
      for (int r = 0; r < 4; r++) {
        const int row = m0 + wm + i * 16 + cr + r;
        const float v = acc[i][j][r] + bval;
        if (OUT_BF16)
          ((unsigned short*)Cout)[(size_t)row * ldc + col] = f2bf(v);
        else
          ((float*)Cout)[(size_t)row * ldc + col] = v;
      }
    }
  }
}

// ---------------- fused RMSNorm + RoPE on q,k heads of qkv buffer ----------------
__global__ __launch_bounds__(256) void norm_rope_kernel(
    unsigned short* __restrict__ qkv,
    const float* __restrict__ qs, const float* __restrict__ ks)
{
  const int wave = threadIdx.x >> 6, lane = threadIdx.x & 63;
  const int gw  = blockIdx.x * 4 + wave;
  const int row = gw / 20;          // 8192 rows
  const int hh  = gw % 20;          // 0..15 q heads, 16..19 k heads
  const bool isq = hh < 16;

  unsigned* p = (unsigned*)(qkv + (size_t)row * NQKV + hh * 128) + lane;
  unsigned d = *p;
  float x1 = bf2f_lo(d), x2 = bf2f_hi(d);

  float ss = x1 * x1 + x2 * x2;
  #pragma unroll
  for (int off = 32; off; off >>= 1) ss += __shfl_xor(ss, off, 64);
  const float r = rsqrtf(ss * (1.f / 128.f) + 1e-6f);

  const float2 sc = ((const float2*)(isq ? qs : ks))[lane];
  float n1 = x1 * r * sc.x;
  float n2 = x2 * r * sc.y;

  const float t = (float)(row & (SS - 1));
  const float freq = __expf((float)lane * (-2.f / 128.f) * 9.21034037197618f); // ln(10000)
  float sn, cs;
  __sincosf(t * freq, &sn, &cs);
  float o1 = n1 * cs - n2 * sn;
  float o2 = n1 * sn + n2 * cs;
  if (isq) { o1 *= (1.f / 128.f); o2 *= (1.f / 128.f); }  // both inv_sqrt_hd factors

  *p = (unsigned)f2bf(o1) | ((unsigned)f2bf(o2) << 16);
}

// ---------------- V transpose: qkv v-slice -> vt[b][g][hd][t] bf16 ----------------
__global__ void vtr_kernel(const unsigned short* __restrict__ qkv,
                           unsigned short* __restrict__ vt){
  __shared__ unsigned short tile[32][34];
  const int hd0 = blockIdx.x * 32, t0 = blockIdx.y * 32, bg = blockIdx.z;
  const int tx = threadIdx.x, ty = threadIdx.y;
  const int b = bg >> 2, g = bg & 3;
  const unsigned short* src = qkv + (size_t)b * SS * NQKV + 2560 + g * HD;
  #pragma unroll
  for (int j = 0; j < 32; j += 8)
    tile[ty + j][tx] = src[(size_t)(t0 + ty + j) * NQKV + hd0 + tx];
  __syncthreads();
  unsigned short* dst = vt + (size_t)bg * HD * SS;
  #pragma unroll
  for (int j = 0; j < 32; j += 8)
    dst[(size_t)(hd0 + ty + j) * SS + t0 + tx] = tile[tx][ty + j];
}

// ---------------- MFMA flash attention ----------------
// One block per (b, h, 64-row q-block). 4 waves, each owns 16 q-rows.
// sK: 64 t-rows x 128 hd, XOR-swizzled 16B granules (gl ^ (row&15))
// sV: 128 hd-rows x 64 t, XOR-swizzled (gl ^ (row&7))
// sP: per-wave 16 x 64 bf16 probs, rows padded to 72 (bank-spread)
__global__ __launch_bounds__(256) void fattn_kernel(
    const unsigned short* __restrict__ qkv,
    const unsigned short* __restrict__ vtb,
    unsigned short* __restrict__ aout)
{
  __shared__ unsigned short sK[64 * 128];     // 16 KB
  __shared__ unsigned short sV[128 * 64];     // 16 KB
  __shared__ unsigned short sP[4][16 * 72];   //  9 KB

  const int lane = threadIdx.x & 63, wave = threadIdx.x >> 6;
  const int quad = lane >> 4, col = lane & 15;
  const int idx = blockIdx.x;
  const int qb = 7 - (idx >> 8);              // heavy (long-K) blocks first
  const int bh = idx & 255;
  const int b = bh >> 4, h = bh & 15, g = h >> 2;

  // Q A-fragments: m=col (q row), k = c*32 + quad*8 + j  -- stay in regs
  const int qrow = qb * 64 + wave * 16 + col;
  const unsigned short* qg = qkv + ((size_t)(b * SS + qrow)) * NQKV + h * HD + quad * 8;
  short8 qf[4];
  #pragma unroll
  for (int c = 0; c < 4; ++c) qf[c] = *(const short8*)(qg + c * 32);

  const unsigned short* kg = qkv + (size_t)b * SS * NQKV + 2048 + g * HD;
  const unsigned short* vg = vtb + ((size_t)(b * GG + g)) * HD * SS;

  floatx4 acc_o[8];
  #pragma unroll
  for (int i = 0; i < 8; ++i) acc_o[i] = (floatx4){0.f, 0.f, 0.f, 0.f};
  float m[4] = {-INFINITY, -INFINITY, -INFINITY, -INFINITY};
  float l[4] = {0.f, 0.f, 0.f, 0.f};

  for (int kt = 0; kt <= qb; ++kt) {
    const int t0 = kt * 64;
    // ---- stage K (64x128) and V^T (128x64), swizzled, via global_load_lds ----
    #pragma unroll
    for (int c = 0; c < 4; ++c) {
      const int ci = c * 4 + wave;
      { const int r  = ci * 4 + (lane >> 4);            // K row 0..63
        const int gl = (lane & 15) ^ (r & 15);
        async_copy16(kg + (size_t)(t0 + r) * NQKV + gl * 8, &sK[ci * 512 + lane * 8]); }
      { const int r  = ci * 8 + (lane >> 3);            // VT row 0..127
        const int gl = (lane & 7) ^ (r & 7);
        async_copy16(vg + (size_t)r * SS + t0 + gl * 8, &sV[ci * 512 + lane * 8]); }
    }
    __syncthreads();

    // ---- S = Q K^T : 4 t-subtiles x 4 k-chunks ----
    floatx4 sc[4];
    #pragma unroll
    for (int s = 0; s < 4; ++s) sc[s] = (floatx4){0.f, 0.f, 0.f, 0.f};
    #pragma unroll
    for (int s = 0; s < 4; ++s) {
      const int trow = s * 16 + col;
      #pragma unroll
      for (int c = 0; c < 4; ++c) {
        const int p = (c * 4 + quad) ^ (trow & 15);
        const short8 kf = *(const short8*)(&sK[trow * 128 + p * 8]);
        sc[s] = __builtin_amdgcn_mfma_f32_16x16x32_bf16(qf[c], kf, sc[s], 0, 0, 0);
      }
    }

    // ---- causal mask (diagonal tile only) ----
    if (kt == qb) {
      #pragma unroll
      for (int s = 0; s < 4; ++s)
        #pragma unroll
        for (int r = 0; r < 4; ++r)
          if (s * 16 + col > wave * 16 + quad * 4 + r) sc[s][r] = -1e30f;
    }

    // ---- online softmax (rows live across 16-lane groups) ----
    float mx[4], alpha[4], lsum[4];
    #pragma unroll
    for (int r = 0; r < 4; ++r) {
      mx[r] = fmaxf(fmaxf(sc[0][r], sc[1][r]), fmaxf(sc[2][r], sc[3][r]));
      #pragma unroll
      for (int off = 8; off; off >>= 1) mx[r] = fmaxf(mx[r], __shfl_xor(mx[r], off, 16));
      mx[r] = fmaxf(mx[r], m[r]);
      alpha[r] = __expf(m[r] - mx[r]);
      m[r] = mx[r];
      lsum[r] = 0.f;
    }
    #pragma unroll
    for (int s = 0; s < 4; ++s)
      #pragma unroll
      for (int r = 0; r < 4; ++r) {
        const float p = __expf(sc[s][r] - m[r]);
        lsum[r] += p;
        sP[wave][(quad * 4 + r) * 72 + s * 16 + col] = f2bf(p);
      }
    #pragma unroll
    for (int r = 0; r < 4; ++r) {
      #pragma unroll
      for (int off = 8; off; off >>= 1) lsum[r] += __shfl_xor(lsum[r], off, 16);
      l[r] = l[r] * alpha[r] + lsum[r];
    }
    #pragma unroll
    for (int n = 0; n < 8; ++n)
      #pragma unroll
      for (int r = 0; r < 4; ++r) acc_o[n][r] *= alpha[r];

    __asm__ volatile("s_waitcnt lgkmcnt(0)" ::: "memory");  // P writes visible to own wave

    // ---- O += P V : P A-frags from LDS, V B-frags from swizzled sV ----
    short8 pf[2];
    #pragma unroll
    for (int kc = 0; kc < 2; ++kc)
      pf[kc] = *(const short8*)(&sP[wave][col * 72 + kc * 32 + quad * 8]);
    #pragma unroll
    for (int n = 0; n < 8; ++n) {
      const int hdrow = n * 16 + col;
      #pragma unroll
      for (int kc = 0; kc < 2; ++kc) {
        const int p = (kc * 4 + quad) ^ (hdrow & 7);
        const short8 vf = *(const short8*)(&sV[hdrow * 64 + p * 8]);
        acc_o[n] = __builtin_amdgcn_mfma_f32_16x16x32_bf16(pf[kc], vf, acc_o[n], 0, 0, 0);
      }
    }
    __syncthreads();
  }

  // ---- epilogue: out = O / l ----
  float inv[4];
  #pragma unroll
  for (int r = 0; r < 4; ++r) inv[r] = 1.f / l[r];
  unsigned short* ob = aout + ((size_t)(b * SS + qb * 64 + wave * 16)) * DD + h * HD;
  #pragma unroll
  for (int n = 0; n < 8; ++n)
    #pragma unroll
    for (int r = 0; r < 4; ++r)
      ob[(size_t)(quad * 4 + r) * DD + n * 16 + col] = f2bf(acc_o[n][r] * inv[r]);
}

extern "C" void kernel_launch(void* const* d_in, const int* in_sizes, int n_in,
                              void* d_out, int out_size, void* d_ws, size_t ws_size,
                              hipStream_t stream) {
  const float* x   = (const float*)d_in[0];
  const float* Wq  = (const float*)d_in[1];
  const float* bq  = (const float*)d_in[2];
  const float* Wk  = (const float*)d_in[3];
  const float* bk  = (const float*)d_in[4];
  const float* Wv  = (const float*)d_in[5];
  const float* bv  = (const float*)d_in[6];
  const float* Wo  = (const float*)d_in[7];
  const float* bo  = (const float*)d_in[8];
  const float* qns = (const float*)d_in[9];
  const float* kns = (const float*)d_in[10];

  char* ws = (char*)d_ws;
  unsigned short* xb    = (unsigned short*)(ws);                 // 8192x2048 bf16 (dead after QKV gemm)
  unsigned short* vtb   = (unsigned short*)(ws);                 // 16x4x128x512 bf16 = 8.4 MB (reuses xb)
  unsigned short* WqkvT = (unsigned short*)(ws + 33554432);      // 3072x2048 bf16
  unsigned short* WoT   = (unsigned short*)(ws + 46137344);      // 2048x2048 bf16
  float*          bqkv  = (float*)         (ws + 54525952);      // 3072 f32
  unsigned short* qkv   = (unsigned short*)(ws + 54538240);      // 8192x3072 bf16
  unsigned short* aout  = (unsigned short*)(ws + 104869888);     // 8192x2048 bf16
  // total 138,424,320 bytes

  dim3 tb(32, 8);
  cvt_x_kernel<<<16384, 256, 0, stream>>>(x, xb, MM * DD / 4);
  tr_cvt_kernel<<<dim3(64, 64), tb, 0, stream>>>(Wq, WqkvT, 2048, 2048);
  tr_cvt_kernel<<<dim3(16, 64), tb, 0, stream>>>(Wk, WqkvT + (size_t)2048 * 2048, 2048, 512);
  tr_cvt_kernel<<<dim3(16, 64), tb, 0, stream>>>(Wv, WqkvT + (size_t)2560 * 2048, 2048, 512);
  tr_cvt_kernel<<<dim3(64, 64), tb, 0, stream>>>(Wo, WoT, 2048, 2048);
  bias_cat_kernel<<<12, 256, 0, stream>>>(bq, bk, bv, bqkv);

  // fused QKV projection: (8192x2048) @ (2048x3072)^T-layout -> qkv bf16
  gemm_bt_kernel<true><<<dim3(24, 64), 256, 0, stream>>>(xb, WqkvT, qkv, bqkv,
                                                         MM, NQKV, DD, NQKV);
  // rmsnorm + rope on q,k
  norm_rope_kernel<<<40960, 256, 0, stream>>>(qkv, qns, kns);
  // V transpose into the now-dead xb region
  vtr_kernel<<<dim3(4, 16, 64), tb, 0, stream>>>(qkv, vtb);
  // MFMA flash attention
  fattn_kernel<<<2048, 256, 0, stream>>>(qkv, vtb, aout);
  // output projection -> fp32 d_out
  gemm_bt_kernel<false><<<dim3(16, 64), 256, 0, stream>>>(aout, WoT, d_out, bo,
                                                          MM, DD, DD, DD);
  (void)in_sizes; (void)n_in; (void)out_size; (void)ws_size;
}

// Round 3
// 484.268 us; speedup vs baseline: 6.3847x; 1.0088x over previous
//
#include <hip/hip_runtime.h>
#include <stdint.h>

typedef __attribute__((ext_vector_type(4))) float floatx4;
typedef __attribute__((ext_vector_type(8))) short short8;

// Problem constants
#define BB 16
#define SS 512
#define DD 2048
#define HH_ 16
#define HD 128
#define GG 4
#define MM (BB*SS)          // 8192
#define NQKV 3072           // 2048 q + 512 k + 512 v

__device__ __forceinline__ unsigned short f2bf(float f){
  unsigned u = __builtin_bit_cast(unsigned, f);
  u += 0x7fffu + ((u >> 16) & 1u);            // RNE
  return (unsigned short)(u >> 16);
}
__device__ __forceinline__ float bf2f_lo(unsigned d){  // low bf16 of a packed dword
  return __builtin_bit_cast(float, d << 16);
}
__device__ __forceinline__ float bf2f_hi(unsigned d){  // high bf16
  return __builtin_bit_cast(float, d & 0xffff0000u);
}

__device__ __forceinline__ void async_copy16(const void* g, void* l){
  __builtin_amdgcn_global_load_lds((const __attribute__((address_space(1))) unsigned*)g,
                                   (__attribute__((address_space(3))) unsigned*)l,
                                   16, 0, 0);
}

// ---------------- fp32 -> bf16 elementwise convert (x) ----------------
__global__ __launch_bounds__(256) void cvt_x_kernel(const float* __restrict__ src,
                                                    unsigned short* __restrict__ dst, int n4){
  int i = blockIdx.x * 256 + threadIdx.x;
  if (i >= n4) return;
  float4 f = ((const float4*)src)[i];
  ushort4 o;
  o.x = f2bf(f.x); o.y = f2bf(f.y); o.z = f2bf(f.z); o.w = f2bf(f.w);
  ((ushort4*)dst)[i] = o;
}

// ---------------- fp32 (R x C) -> bf16 transpose (C x R) ----------------
__global__ void tr_cvt_kernel(const float* __restrict__ src, unsigned short* __restrict__ dst,
                              int R, int C){
  __shared__ float tile[32][33];
  int c0 = blockIdx.x * 32, r0 = blockIdx.y * 32;
  int tx = threadIdx.x, ty = threadIdx.y;
  #pragma unroll
  for (int j = 0; j < 32; j += 8)
    tile[ty + j][tx] = src[(size_t)(r0 + ty + j) * C + (c0 + tx)];
  __syncthreads();
  #pragma unroll
  for (int j = 0; j < 32; j += 8)
    dst[(size_t)(c0 + ty + j) * R + (r0 + tx)] = f2bf(tile[tx][ty + j]);
}

// ---------------- concat bias [bq | bk | bv] ----------------
__global__ void bias_cat_kernel(const float* __restrict__ bq, const float* __restrict__ bk,
                                const float* __restrict__ bv, float* __restrict__ out){
  int i = blockIdx.x * 256 + threadIdx.x;
  if (i >= NQKV) return;
  out[i] = (i < 2048) ? bq[i] : (i < 2560 ? bk[i - 2048] : bv[i - 2560]);
}

// ---------------- bf16 GEMM: C = A(MxK) @ Bt(NxK)^T + bias ----------------
// m97-style 128x128 tile, BK=32, global_load_lds(16B).
// LDS rows (32 ushorts = 4 x 16B granules) are XOR-swizzled: logical granule g of
// row r lives at physical slot g ^ ((r>>1)&3). Swizzle is applied at staging by
// permuting WHICH global granule each lane fetches (LDS dest stays base+lane*16,
// the wave-uniform global_load_lds pattern). This makes each 8-lane phase of the
// fragment ds_read_b128 cover all 8 granule-slots -> conflict-free.
template<bool OUT_BF16>
__global__ __launch_bounds__(256) void gemm_bt_kernel(
    const unsigned short* __restrict__ A,
    const unsigned short* __restrict__ Bt,
    void* __restrict__ Cout,
    const float* __restrict__ bias,
    int M, int N, int K, int ldc)
{
  __shared__ unsigned short sA[128 * 32];   // 8 KB
  __shared__ unsigned short sB[128 * 32];   // 8 KB
  const int tid  = threadIdx.x;
  const int wave = tid >> 6;
  const int lane = tid & 63;
  const int m0 = blockIdx.y * 128;
  const int n0 = blockIdx.x * 128;
  const int wm = (wave >> 1) * 64;
  const int wn = (wave & 1) * 64;

  floatx4 acc[4][4];
  #pragma unroll
  for (int i = 0; i < 4; i++)
    #pragma unroll
    for (int j = 0; j < 4; j++)
      acc[i][j] = (floatx4){0.f, 0.f, 0.f, 0.f};

  // staging: wave w fills LDS rows [32w, 32w+32), two 1KB calls of 16 rows each.
  // lane l -> row l>>2, physical slot l&3; fetch logical granule (l&3)^sigma,
  // sigma = ((row)>>1)&3 = ((l>>3)&3) (row-base offsets 32w and +16 are 0 mod 4 after >>1... both chunks give same sigma).
  const int rA = 32 * wave + (lane >> 2);
  const int cH = (((lane & 3) ^ ((lane >> 3) & 3))) * 8;   // swizzled ushort offset
  const unsigned short* gA0 = A  + (size_t)(m0 + rA)      * K + cH;
  const unsigned short* gA1 = A  + (size_t)(m0 + rA + 16) * K + cH;
  const unsigned short* gB0 = Bt + (size_t)(n0 + rA)      * K + cH;
  const unsigned short* gB1 = Bt + (size_t)(n0 + rA + 16) * K + cH;
  unsigned short* lA0 = &sA[wave * 1024];
  unsigned short* lA1 = &sA[wave * 1024 + 512];
  unsigned short* lB0 = &sB[wave * 1024];
  unsigned short* lB1 = &sB[wave * 1024 + 512];

  // fragment read: lane needs row (l&15), logical granule q=(l>>4);
  // physical slot = q ^ ((l&15)>>1 & 3)  (tile-row bases wm+i*16 are 0 mod 4 after >>1)
  const int fOffBase = (lane & 15) * 32 + (((lane >> 4) ^ (((lane & 15) >> 1) & 3)) * 8);

  for (int k0 = 0; k0 < K; k0 += 32) {
    async_copy16(gA0 + k0, lA0);
    async_copy16(gA1 + k0, lA1);
    async_copy16(gB0 + k0, lB0);
    async_copy16(gB1 + k0, lB1);
    __syncthreads();

    short8 aF[4], bF[4];
    #pragma unroll
    for (int i = 0; i < 4; i++)
      aF[i] = *(const short8*)(&sA[(wm + i * 16) * 32 + fOffBase]);
    #pragma unroll
    for (int j = 0; j < 4; j++)
      bF[j] = *(const short8*)(&sB[(wn + j * 16) * 32 + fOffBase]);

    #pragma unroll
    for (int i = 0; i < 4; i++)
      #pragma unroll
      for (int j = 0; j < 4; j++)
        acc[i][j] = __builtin_amdgcn_mfma_f32_16x16x32_bf16(aF[i], bF[j], acc[i][j], 0, 0, 0);
    __syncthreads();
  }

  const int cr = (lane >> 4) * 4;
  const int cc = lane & 15;
  #pragma unroll
  for (int j = 0; j < 4; j++) {
    const int col = n0 + wn + j * 16 + cc;
    const float bval = bias[col];
    #pragma unroll
    for (int i = 0; i < 4; i++) {
      #pragma unroll
      for (int r = 0; r < 4; r++) {
        const int row = m0 + wm + i * 16 + cr + r;
        const float v = acc[i][j][r] + bval;
        if (OUT_BF16)
          ((unsigned short*)Cout)[(size_t)row * ldc + col] = f2bf(v);
        else
          ((float*)Cout)[(size_t)row * ldc + col] = v;
      }
    }
  }
}

// ---------------- fused RMSNorm + RoPE on q,k heads of qkv buffer ----------------
__global__ __launch_bounds__(256) void norm_rope_kernel(
    unsigned short* __restrict__ qkv,
    const float* __restrict__ qs, const float* __restrict__ ks)
{
  const int wave = threadIdx.x >> 6, lane = threadIdx.x & 63;
  const int gw  = blockIdx.x * 4 + wave;
  const int row = gw / 20;          // 8192 rows
  const int hh  = gw % 20;          // 0..15 q heads, 16..19 k heads
  const bool isq = hh < 16;

  unsigned* p = (unsigned*)(qkv + (size_t)row * NQKV + hh * 128) + lane;
  unsigned d = *p;
  float x1 = bf2f_lo(d), x2 = bf2f_hi(d);

  float ss = x1 * x1 + x2 * x2;
  #pragma unroll
  for (int off = 32; off; off >>= 1) ss += __shfl_xor(ss, off, 64);
  const float r = rsqrtf(ss * (1.f / 128.f) + 1e-6f);

  const float2 sc = ((const float2*)(isq ? qs : ks))[lane];
  float n1 = x1 * r * sc.x;
  float n2 = x2 * r * sc.y;

  const float t = (float)(row & (SS - 1));
  const float freq = __expf((float)lane * (-2.f / 128.f) * 9.21034037197618f); // ln(10000)
  float sn, cs;
  __sincosf(t * freq, &sn, &cs);
  float o1 = n1 * cs - n2 * sn;
  float o2 = n1 * sn + n2 * cs;
  if (isq) { o1 *= (1.f / 128.f); o2 *= (1.f / 128.f); }  // both inv_sqrt_hd factors

  *p = (unsigned)f2bf(o1) | ((unsigned)f2bf(o2) << 16);
}

// ---------------- V transpose: qkv v-slice -> vt[b][g][hd][t] bf16 ----------------
__global__ void vtr_kernel(const unsigned short* __restrict__ qkv,
                           unsigned short* __restrict__ vt){
  __shared__ unsigned short tile[32][34];
  const int hd0 = blockIdx.x * 32, t0 = blockIdx.y * 32, bg = blockIdx.z;
  const int tx = threadIdx.x, ty = threadIdx.y;
  const int b = bg >> 2, g = bg & 3;
  const unsigned short* src = qkv + (size_t)b * SS * NQKV + 2560 + g * HD;
  #pragma unroll
  for (int j = 0; j < 32; j += 8)
    tile[ty + j][tx] = src[(size_t)(t0 + ty + j) * NQKV + hd0 + tx];
  __syncthreads();
  unsigned short* dst = vt + (size_t)bg * HD * SS;
  #pragma unroll
  for (int j = 0; j < 32; j += 8)
    dst[(size_t)(hd0 + ty + j) * SS + t0 + tx] = tile[tx][ty + j];
}

// ---------------- MFMA flash attention ----------------
__global__ __launch_bounds__(256) void fattn_kernel(
    const unsigned short* __restrict__ qkv,
    const unsigned short* __restrict__ vtb,
    unsigned short* __restrict__ aout)
{
  __shared__ unsigned short sK[64 * 128];     // 16 KB
  __shared__ unsigned short sV[128 * 64];     // 16 KB
  __shared__ unsigned short sP[4][16 * 72];   //  9 KB

  const int lane = threadIdx.x & 63, wave = threadIdx.x >> 6;
  const int quad = lane >> 4, col = lane & 15;
  const int idx = blockIdx.x;
  const int qb = 7 - (idx >> 8);              // heavy (long-K) blocks first
  const int bh = idx & 255;
  const int b = bh >> 4, h = bh & 15, g = h >> 2;

  const int qrow = qb * 64 + wave * 16 + col;
  const unsigned short* qg = qkv + ((size_t)(b * SS + qrow)) * NQKV + h * HD + quad * 8;
  short8 qf[4];
  #pragma unroll
  for (int c = 0; c < 4; ++c) qf[c] = *(const short8*)(qg + c * 32);

  const unsigned short* kg = qkv + (size_t)b * SS * NQKV + 2048 + g * HD;
  const unsigned short* vg = vtb + ((size_t)(b * GG + g)) * HD * SS;

  floatx4 acc_o[8];
  #pragma unroll
  for (int i = 0; i < 8; ++i) acc_o[i] = (floatx4){0.f, 0.f, 0.f, 0.f};
  float m[4] = {-INFINITY, -INFINITY, -INFINITY, -INFINITY};
  float l[4] = {0.f, 0.f, 0.f, 0.f};

  for (int kt = 0; kt <= qb; ++kt) {
    const int t0 = kt * 64;
    #pragma unroll
    for (int c = 0; c < 4; ++c) {
      const int ci = c * 4 + wave;
      { const int r  = ci * 4 + (lane >> 4);            // K row 0..63
        const int gl = (lane & 15) ^ (r & 15);
        async_copy16(kg + (size_t)(t0 + r) * NQKV + gl * 8, &sK[ci * 512 + lane * 8]); }
      { const int r  = ci * 8 + (lane >> 3);            // VT row 0..127
        const int gl = (lane & 7) ^ (r & 7);
        async_copy16(vg + (size_t)r * SS + t0 + gl * 8, &sV[ci * 512 + lane * 8]); }
    }
    __syncthreads();

    floatx4 sc[4];
    #pragma unroll
    for (int s = 0; s < 4; ++s) sc[s] = (floatx4){0.f, 0.f, 0.f, 0.f};
    #pragma unroll
    for (int s = 0; s < 4; ++s) {
      const int trow = s * 16 + col;
      #pragma unroll
      for (int c = 0; c < 4; ++c) {
        const int p = (c * 4 + quad) ^ (trow & 15);
        const short8 kf = *(const short8*)(&sK[trow * 128 + p * 8]);
        sc[s] = __builtin_amdgcn_mfma_f32_16x16x32_bf16(qf[c], kf, sc[s], 0, 0, 0);
      }
    }

    if (kt == qb) {
      #pragma unroll
      for (int s = 0; s < 4; ++s)
        #pragma unroll
        for (int r = 0; r < 4; ++r)
          if (s * 16 + col > wave * 16 + quad * 4 + r) sc[s][r] = -1e30f;
    }

    float mx[4], alpha[4], lsum[4];
    #pragma unroll
    for (int r = 0; r < 4; ++r) {
      mx[r] = fmaxf(fmaxf(sc[0][r], sc[1][r]), fmaxf(sc[2][r], sc[3][r]));
      #pragma unroll
      for (int off = 8; off; off >>= 1) mx[r] = fmaxf(mx[r], __shfl_xor(mx[r], off, 16));
      mx[r] = fmaxf(mx[r], m[r]);
      alpha[r] = __expf(m[r] - mx[r]);
      m[r] = mx[r];
      lsum[r] = 0.f;
    }
    #pragma unroll
    for (int s = 0; s < 4; ++s)
      #pragma unroll
      for (int r = 0; r < 4; ++r) {
        const float p = __expf(sc[s][r] - m[r]);
        lsum[r] += p;
        sP[wave][(quad * 4 + r) * 72 + s * 16 + col] = f2bf(p);
      }
    #pragma unroll
    for (int r = 0; r < 4; ++r) {
      #pragma unroll
      for (int off = 8; off; off >>= 1) lsum[r] += __shfl_xor(lsum[r], off, 16);
      l[r] = l[r] * alpha[r] + lsum[r];
    }
    #pragma unroll
    for (int n = 0; n < 8; ++n)
      #pragma unroll
      for (int r = 0; r < 4; ++r) acc_o[n][r] *= alpha[r];

    __asm__ volatile("s_waitcnt lgkmcnt(0)" ::: "memory");  // P writes visible to own wave

    short8 pf[2];
    #pragma unroll
    for (int kc = 0; kc < 2; ++kc)
      pf[kc] = *(const short8*)(&sP[wave][col * 72 + kc * 32 + quad * 8]);
    #pragma unroll
    for (int n = 0; n < 8; ++n) {
      const int hdrow = n * 16 + col;
      #pragma unroll
      for (int kc = 0; kc < 2; ++kc) {
        const int p = (kc * 4 + quad) ^ (hdrow & 7);
        const short8 vf = *(const short8*)(&sV[hdrow * 64 + p * 8]);
        acc_o[n] = __builtin_amdgcn_mfma_f32_16x16x32_bf16(pf[kc], vf, acc_o[n], 0, 0, 0);
      }
    }
    __syncthreads();
  }

  float inv[4];
  #pragma unroll
  for (int r = 0; r < 4; ++r) inv[r] = 1.f / l[r];
  unsigned short* ob = aout + ((size_t)(b * SS + qb * 64 + wave * 16)) * DD + h * HD;
  #pragma unroll
  for (int n = 0; n < 8; ++n)
    #pragma unroll
    for (int r = 0; r < 4; ++r)
      ob[(size_t)(quad * 4 + r) * DD + n * 16 + col] = f2bf(acc_o[n][r] * inv[r]);
}

extern "C" void kernel_launch(void* const* d_in, const int* in_sizes, int n_in,
                              void* d_out, int out_size, void* d_ws, size_t ws_size,
                              hipStream_t stream) {
  const float* x   = (const float*)d_in[0];
  const float* Wq  = (const float*)d_in[1];
  const float* bq  = (const float*)d_in[2];
  const float* Wk  = (const float*)d_in[3];
  const float* bk  = (const float*)d_in[4];
  const float* Wv  = (const float*)d_in[5];
  const float* bv  = (const float*)d_in[6];
  const float* Wo  = (const float*)d_in[7];
  const float* bo  = (const float*)d_in[8];
  const float* qns = (const float*)d_in[9];
  const float* kns = (const float*)d_in[10];

  char* ws = (char*)d_ws;
  unsigned short* xb    = (unsigned short*)(ws);                 // 8192x2048 bf16 (dead after QKV gemm)
  unsigned short* vtb   = (unsigned short*)(ws);                 // 16x4x128x512 bf16 (reuses xb)
  unsigned short* WqkvT = (unsigned short*)(ws + 33554432);      // 3072x2048 bf16
  unsigned short* WoT   = (unsigned short*)(ws + 46137344);      // 2048x2048 bf16
  float*          bqkv  = (float*)         (ws + 54525952);      // 3072 f32
  unsigned short* qkv   = (unsigned short*)(ws + 54538240);      // 8192x3072 bf16
  unsigned short* aout  = (unsigned short*)(ws + 104869888);     // 8192x2048 bf16
  // total 138,424,320 bytes

  dim3 tb(32, 8);
  cvt_x_kernel<<<16384, 256, 0, stream>>>(x, xb, MM * DD / 4);
  tr_cvt_kernel<<<dim3(64, 64), tb, 0, stream>>>(Wq, WqkvT, 2048, 2048);
  tr_cvt_kernel<<<dim3(16, 64), tb, 0, stream>>>(Wk, WqkvT + (size_t)2048 * 2048, 2048, 512);
  tr_cvt_kernel<<<dim3(16, 64), tb, 0, stream>>>(Wv, WqkvT + (size_t)2560 * 2048, 2048, 512);
  tr_cvt_kernel<<<dim3(64, 64), tb, 0, stream>>>(Wo, WoT, 2048, 2048);
  bias_cat_kernel<<<12, 256, 0, stream>>>(bq, bk, bv, bqkv);

  // fused QKV projection: (8192x2048) @ (2048x3072)^T-layout -> qkv bf16
  gemm_bt_kernel<true><<<dim3(24, 64), 256, 0, stream>>>(xb, WqkvT, qkv, bqkv,
                                                         MM, NQKV, DD, NQKV);
  // rmsnorm + rope on q,k
  norm_rope_kernel<<<40960, 256, 0, stream>>>(qkv, qns, kns);
  // V transpose into the now-dead xb region
  vtr_kernel<<<dim3(4, 16, 64), tb, 0, stream>>>(qkv, vtb);
  // MFMA flash attention
  fattn_kernel<<<2048, 256, 0, stream>>>(qkv, vtb, aout);
  // output projection -> fp32 d_out
  gemm_bt_kernel<false><<<dim3(16, 64), 256, 0, stream>>>(aout, WoT, d_out, bo,
                                                          MM, DD, DD, DD);
  (void)in_sizes; (void)n_in; (void)out_size; (void)ws_size;
}

// Round 4
// 441.489 us; speedup vs baseline: 7.0034x; 1.0969x over previous
//
#include <hip/hip_runtime.h>
#include <stdint.h>

typedef __attribute__((ext_vector_type(4))) float floatx4;
typedef __attribute__((ext_vector_type(16))) float floatx16;
typedef __attribute__((ext_vector_type(8))) short short8;

// Problem constants
#define BB 16
#define SS 512
#define DD 2048
#define HH_ 16
#define HD 128
#define GG 4
#define MM (BB*SS)          // 8192
#define NQKV 3072           // 2048 q + 512 k + 512 v

__device__ __forceinline__ unsigned short f2bf(float f){
  unsigned u = __builtin_bit_cast(unsigned, f);
  u += 0x7fffu + ((u >> 16) & 1u);            // RNE
  return (unsigned short)(u >> 16);
}
__device__ __forceinline__ float bf2f_lo(unsigned d){
  return __builtin_bit_cast(float, d << 16);
}
__device__ __forceinline__ float bf2f_hi(unsigned d){
  return __builtin_bit_cast(float, d & 0xffff0000u);
}

__device__ __forceinline__ void async_copy16(const void* g, void* l){
  __builtin_amdgcn_global_load_lds((const __attribute__((address_space(1))) unsigned*)g,
                                   (__attribute__((address_space(3))) unsigned*)l,
                                   16, 0, 0);
}

// ---------------- fused prep: cvt_x | 4x transpose | bias concat ----------------
// block ranges: [0,16384) cvt_x; [16384,20480) Wq; [20480,21504) Wk;
// [21504,22528) Wv; [22528,26624) Wo; [26624,26636) bias
#define PB_CVT   16384
#define PB_TRQ   (PB_CVT + 4096)
#define PB_TRK   (PB_TRQ + 1024)
#define PB_TRV   (PB_TRK + 1024)
#define PB_TRO   (PB_TRV + 4096)
#define PB_ALL   (PB_TRO + 12)

__global__ __launch_bounds__(256) void prep_kernel(
    const float* __restrict__ x,
    const float* __restrict__ Wq, const float* __restrict__ Wk,
    const float* __restrict__ Wv, const float* __restrict__ Wo,
    const float* __restrict__ bq, const float* __restrict__ bk,
    const float* __restrict__ bv,
    unsigned short* __restrict__ xb, unsigned short* __restrict__ WqkvT,
    unsigned short* __restrict__ WoT, float* __restrict__ bqkv)
{
  __shared__ float tile[32][33];
  const int bid = blockIdx.x, tid = threadIdx.x;

  if (bid < PB_CVT) {                       // ---- x fp32 -> bf16 ----
    const int i = bid * 256 + tid;
    float4 f = ((const float4*)x)[i];
    ushort4 o;
    o.x = f2bf(f.x); o.y = f2bf(f.y); o.z = f2bf(f.z); o.w = f2bf(f.w);
    ((ushort4*)xb)[i] = o;
    return;
  }
  if (bid < PB_TRO) {                       // ---- W transpose+cvt ----
    const float* src; unsigned short* dst; int R, C, b2;
    if (bid < PB_TRQ)      { src = Wq; dst = WqkvT;                          R = 2048; C = 2048; b2 = bid - PB_CVT; }
    else if (bid < PB_TRK) { src = Wk; dst = WqkvT + (size_t)2048 * 2048;    R = 2048; C = 512;  b2 = bid - PB_TRQ; }
    else if (bid < PB_TRV) { src = Wv; dst = WqkvT + (size_t)2560 * 2048;    R = 2048; C = 512;  b2 = bid - PB_TRK; }
    else                   { src = Wo; dst = WoT;                            R = 2048; C = 2048; b2 = bid - PB_TRV; }
    const int nbx = C >> 5;
    const int c0 = (b2 % nbx) * 32, r0 = (b2 / nbx) * 32;
    const int tx = tid & 31, ty = tid >> 5;          // 32 x 8
    #pragma unroll
    for (int j = 0; j < 32; j += 8)
      tile[ty + j][tx] = src[(size_t)(r0 + ty + j) * C + (c0 + tx)];
    __syncthreads();
    #pragma unroll
    for (int j = 0; j < 32; j += 8)
      dst[(size_t)(c0 + ty + j) * R + (r0 + tx)] = f2bf(tile[tx][ty + j]);
    return;
  }
  {                                         // ---- bias concat ----
    const int i = (bid - PB_TRO) * 256 + tid;
    if (i < NQKV)
      bqkv[i] = (i < 2048) ? bq[i] : (i < 2560 ? bk[i - 2048] : bv[i - 2560]);
  }
}

// ---------------- bf16 GEMM: C = A(MxK) @ Bt(NxK)^T + bias ----------------
// 128x128 tile, BK=64, 32x32x16 MFMA (2x2 per wave), global_load_lds(16B).
// LDS rows = 64 ushorts = 8 x 16B granules; logical granule g of row r lives at
// physical slot g ^ (r&7) (full 3-bit XOR: row stride = 128B = exactly 32 banks,
// so each 8-lane read phase needs all 8 slots distinct). Swizzle applied at
// staging by permuting which global granule each lane fetches; LDS dest stays
// base + lane*16 (wave-uniform global_load_lds pattern).
template<bool OUT_BF16>
__global__ __launch_bounds__(256) void gemm_bt_kernel(
    const unsigned short* __restrict__ A,
    const unsigned short* __restrict__ Bt,
    void* __restrict__ Cout,
    const float* __restrict__ bias,
    int M, int N, int K, int ldc)
{
  __shared__ unsigned short sA[128 * 64];   // 16 KB
  __shared__ unsigned short sB[128 * 64];   // 16 KB
  const int tid  = threadIdx.x;
  const int wave = tid >> 6;
  const int lane = tid & 63;
  const int m0 = blockIdx.y * 128;
  const int n0 = blockIdx.x * 128;
  const int wm = (wave >> 1) * 64;
  const int wn = (wave & 1) * 64;

  floatx16 acc[2][2];
  #pragma unroll
  for (int i = 0; i < 2; i++)
    #pragma unroll
    for (int j = 0; j < 2; j++)
      #pragma unroll
      for (int r = 0; r < 16; r++) acc[i][j][r] = 0.f;

  // staging: wave w fills rows [32w,32w+32), 4 calls x 8 rows; lane l -> row
  // 32w+8c+(l>>3), slot l&7, fetches logical granule (l&7)^((l>>3)&7)
  const int sglog = (lane & 7) ^ ((lane >> 3) & 7);
  const unsigned short* gA = A  + (size_t)(m0 + 32 * wave + (lane >> 3)) * K + sglog * 8;
  const unsigned short* gB = Bt + (size_t)(n0 + 32 * wave + (lane >> 3)) * K + sglog * 8;
  unsigned short* lA = &sA[32 * wave * 64 + lane * 8];
  unsigned short* lB = &sB[32 * wave * 64 + lane * 8];

  for (int k0 = 0; k0 < K; k0 += 64) {
    #pragma unroll
    for (int c = 0; c < 4; ++c) {
      async_copy16(gA + (size_t)c * 8 * K + k0, lA + c * 512);
      async_copy16(gB + (size_t)c * 8 * K + k0, lB + c * 512);
    }
    __syncthreads();

    #pragma unroll
    for (int kh = 0; kh < 4; ++kh) {
      // A[m=lane&31][k=kh*16+(lane>>5)*8+j]; granule = kh*2+(lane>>5);
      // slot = granule ^ (row&7), row&7 == lane&7
      const int slot = (kh * 2 + (lane >> 5)) ^ (lane & 7);
      short8 aF[2], bF[2];
      #pragma unroll
      for (int i = 0; i < 2; ++i)
        aF[i] = *(const short8*)(&sA[(wm + i * 32 + (lane & 31)) * 64 + slot * 8]);
      #pragma unroll
      for (int j = 0; j < 2; ++j)
        bF[j] = *(const short8*)(&sB[(wn + j * 32 + (lane & 31)) * 64 + slot * 8]);
      #pragma unroll
      for (int i = 0; i < 2; ++i)
        #pragma unroll
        for (int j = 0; j < 2; ++j)
          acc[i][j] = __builtin_amdgcn_mfma_f32_32x32x16_bf16(aF[i], bF[j], acc[i][j], 0, 0, 0);
    }
    __syncthreads();
  }

  // epilogue: 32x32 C/D layout col=lane&31, row=(reg&3)+8*(reg>>2)+4*(lane>>5)
  const int cc = lane & 31;
  const int rb = 4 * (lane >> 5);
  #pragma unroll
  for (int j = 0; j < 2; j++) {
    const int col = n0 + wn + j * 32 + cc;
    const float bval = bias[col];
    #pragma unroll
    for (int i = 0; i < 2; i++) {
      #pragma unroll
      for (int reg = 0; reg < 16; reg++) {
        const int row = m0 + wm + i * 32 + (reg & 3) + 8 * (reg >> 2) + rb;
        const float v = acc[i][j][reg] + bval;
        if (OUT_BF16)
          ((unsigned short*)Cout)[(size_t)row * ldc + col] = f2bf(v);
        else
          ((float*)Cout)[(size_t)row * ldc + col] = v;
      }
    }
  }
}

// ---------------- fused RMSNorm+RoPE (q,k) | V transpose ----------------
// blocks [0,40960): norm_rope; [40960,45056): vtr
__global__ __launch_bounds__(256) void norm_vtr_kernel(
    unsigned short* __restrict__ qkv,
    const float* __restrict__ qs, const float* __restrict__ ks,
    unsigned short* __restrict__ vt)
{
  __shared__ unsigned short tileV[32][34];
  const int bid = blockIdx.x, tid = threadIdx.x;

  if (bid < 40960) {
    const int wave = tid >> 6, lane = tid & 63;
    const int gw  = bid * 4 + wave;
    const int row = gw / 20;
    const int hh  = gw % 20;          // 0..15 q heads, 16..19 k heads
    const bool isq = hh < 16;

    unsigned* p = (unsigned*)(qkv + (size_t)row * NQKV + hh * 128) + lane;
    unsigned d = *p;
    float x1 = bf2f_lo(d), x2 = bf2f_hi(d);

    float ss = x1 * x1 + x2 * x2;
    #pragma unroll
    for (int off = 32; off; off >>= 1) ss += __shfl_xor(ss, off, 64);
    const float r = rsqrtf(ss * (1.f / 128.f) + 1e-6f);

    const float2 sc = ((const float2*)(isq ? qs : ks))[lane];
    float n1 = x1 * r * sc.x;
    float n2 = x2 * r * sc.y;

    const float t = (float)(row & (SS - 1));
    const float freq = __expf((float)lane * (-2.f / 128.f) * 9.21034037197618f);
    float sn, cs;
    __sincosf(t * freq, &sn, &cs);
    float o1 = n1 * cs - n2 * sn;
    float o2 = n1 * sn + n2 * cs;
    if (isq) { o1 *= (1.f / 128.f); o2 *= (1.f / 128.f); }

    *p = (unsigned)f2bf(o1) | ((unsigned)f2bf(o2) << 16);
    return;
  }
  {
    const int b2 = bid - 40960;
    const int hd0 = (b2 & 3) * 32, t0 = ((b2 >> 2) & 15) * 32, bg = b2 >> 6;
    const int tx = tid & 31, ty = tid >> 5;
    const int b = bg >> 2, g = bg & 3;
    const unsigned short* src = qkv + (size_t)b * SS * NQKV + 2560 + g * HD;
    #pragma unroll
    for (int j = 0; j < 32; j += 8)
      tileV[ty + j][tx] = src[(size_t)(t0 + ty + j) * NQKV + hd0 + tx];
    __syncthreads();
    unsigned short* dst = vt + (size_t)bg * HD * SS;
    #pragma unroll
    for (int j = 0; j < 32; j += 8)
      dst[(size_t)(hd0 + ty + j) * SS + t0 + tx] = tileV[tx][ty + j];
  }
}

// ---------------- MFMA flash attention ----------------
__global__ __launch_bounds__(256) void fattn_kernel(
    const unsigned short* __restrict__ qkv,
    const unsigned short* __restrict__ vtb,
    unsigned short* __restrict__ aout)
{
  __shared__ unsigned short sK[64 * 128];     // 16 KB
  __shared__ unsigned short sV[128 * 64];     // 16 KB
  __shared__ unsigned short sP[4][16 * 72];   //  9 KB

  const int lane = threadIdx.x & 63, wave = threadIdx.x >> 6;
  const int quad = lane >> 4, col = lane & 15;
  const int idx = blockIdx.x;
  const int qb = 7 - (idx >> 8);              // heavy (long-K) blocks first
  const int bh = idx & 255;
  const int b = bh >> 4, h = bh & 15, g = h >> 2;

  const int qrow = qb * 64 + wave * 16 + col;
  const unsigned short* qg = qkv + ((size_t)(b * SS + qrow)) * NQKV + h * HD + quad * 8;
  short8 qf[4];
  #pragma unroll
  for (int c = 0; c < 4; ++c) qf[c] = *(const short8*)(qg + c * 32);

  const unsigned short* kg = qkv + (size_t)b * SS * NQKV + 2048 + g * HD;
  const unsigned short* vg = vtb + ((size_t)(b * GG + g)) * HD * SS;

  floatx4 acc_o[8];
  #pragma unroll
  for (int i = 0; i < 8; ++i) acc_o[i] = (floatx4){0.f, 0.f, 0.f, 0.f};
  float m[4] = {-INFINITY, -INFINITY, -INFINITY, -INFINITY};
  float l[4] = {0.f, 0.f, 0.f, 0.f};

  for (int kt = 0; kt <= qb; ++kt) {
    const int t0 = kt * 64;
    #pragma unroll
    for (int c = 0; c < 4; ++c) {
      const int ci = c * 4 + wave;
      { const int r  = ci * 4 + (lane >> 4);
        const int gl = (lane & 15) ^ (r & 15);
        async_copy16(kg + (size_t)(t0 + r) * NQKV + gl * 8, &sK[ci * 512 + lane * 8]); }
      { const int r  = ci * 8 + (lane >> 3);
        const int gl = (lane & 7) ^ (r & 7);
        async_copy16(vg + (size_t)r * SS + t0 + gl * 8, &sV[ci * 512 + lane * 8]); }
    }
    __syncthreads();

    floatx4 sc[4];
    #pragma unroll
    for (int s = 0; s < 4; ++s) sc[s] = (floatx4){0.f, 0.f, 0.f, 0.f};
    #pragma unroll
    for (int s = 0; s < 4; ++s) {
      const int trow = s * 16 + col;
      #pragma unroll
      for (int c = 0; c < 4; ++c) {
        const int p = (c * 4 + quad) ^ (trow & 15);
        const short8 kf = *(const short8*)(&sK[trow * 128 + p * 8]);
        sc[s] = __builtin_amdgcn_mfma_f32_16x16x32_bf16(qf[c], kf, sc[s], 0, 0, 0);
      }
    }

    if (kt == qb) {
      #pragma unroll
      for (int s = 0; s < 4; ++s)
        #pragma unroll
        for (int r = 0; r < 4; ++r)
          if (s * 16 + col > wave * 16 + quad * 4 + r) sc[s][r] = -1e30f;
    }

    float mx[4], alpha[4], lsum[4];
    #pragma unroll
    for (int r = 0; r < 4; ++r) {
      mx[r] = fmaxf(fmaxf(sc[0][r], sc[1][r]), fmaxf(sc[2][r], sc[3][r]));
      #pragma unroll
      for (int off = 8; off; off >>= 1) mx[r] = fmaxf(mx[r], __shfl_xor(mx[r], off, 16));
      mx[r] = fmaxf(mx[r], m[r]);
      alpha[r] = __expf(m[r] - mx[r]);
      m[r] = mx[r];
      lsum[r] = 0.f;
    }
    #pragma unroll
    for (int s = 0; s < 4; ++s)
      #pragma unroll
      for (int r = 0; r < 4; ++r) {
        const float p = __expf(sc[s][r] - m[r]);
        lsum[r] += p;
        sP[wave][(quad * 4 + r) * 72 + s * 16 + col] = f2bf(p);
      }
    #pragma unroll
    for (int r = 0; r < 4; ++r) {
      #pragma unroll
      for (int off = 8; off; off >>= 1) lsum[r] += __shfl_xor(lsum[r], off, 16);
      l[r] = l[r] * alpha[r] + lsum[r];
    }
    #pragma unroll
    for (int n = 0; n < 8; ++n)
      #pragma unroll
      for (int r = 0; r < 4; ++r) acc_o[n][r] *= alpha[r];

    __asm__ volatile("s_waitcnt lgkmcnt(0)" ::: "memory");

    short8 pf[2];
    #pragma unroll
    for (int kc = 0; kc < 2; ++kc)
      pf[kc] = *(const short8*)(&sP[wave][col * 72 + kc * 32 + quad * 8]);
    #pragma unroll
    for (int n = 0; n < 8; ++n) {
      const int hdrow = n * 16 + col;
      #pragma unroll
      for (int kc = 0; kc < 2; ++kc) {
        const int p = (kc * 4 + quad) ^ (hdrow & 7);
        const short8 vf = *(const short8*)(&sV[hdrow * 64 + p * 8]);
        acc_o[n] = __builtin_amdgcn_mfma_f32_16x16x32_bf16(pf[kc], vf, acc_o[n], 0, 0, 0);
      }
    }
    __syncthreads();
  }

  float inv[4];
  #pragma unroll
  for (int r = 0; r < 4; ++r) inv[r] = 1.f / l[r];
  unsigned short* ob = aout + ((size_t)(b * SS + qb * 64 + wave * 16)) * DD + h * HD;
  #pragma unroll
  for (int n = 0; n < 8; ++n)
    #pragma unroll
    for (int r = 0; r < 4; ++r)
      ob[(size_t)(quad * 4 + r) * DD + n * 16 + col] = f2bf(acc_o[n][r] * inv[r]);
}

extern "C" void kernel_launch(void* const* d_in, const int* in_sizes, int n_in,
                              void* d_out, int out_size, void* d_ws, size_t ws_size,
                              hipStream_t stream) {
  const float* x   = (const float*)d_in[0];
  const float* Wq  = (const float*)d_in[1];
  const float* bq  = (const float*)d_in[2];
  const float* Wk  = (const float*)d_in[3];
  const float* bk  = (const float*)d_in[4];
  const float* Wv  = (const float*)d_in[5];
  const float* bv  = (const float*)d_in[6];
  const float* Wo  = (const float*)d_in[7];
  const float* bo  = (const float*)d_in[8];
  const float* qns = (const float*)d_in[9];
  const float* kns = (const float*)d_in[10];

  char* ws = (char*)d_ws;
  unsigned short* xb    = (unsigned short*)(ws);                 // 8192x2048 bf16 (dead after QKV gemm)
  unsigned short* vtb   = (unsigned short*)(ws);                 // 16x4x128x512 bf16 (reuses xb)
  unsigned short* WqkvT = (unsigned short*)(ws + 33554432);      // 3072x2048 bf16
  unsigned short* WoT   = (unsigned short*)(ws + 46137344);      // 2048x2048 bf16
  float*          bqkv  = (float*)         (ws + 54525952);      // 3072 f32
  unsigned short* qkv   = (unsigned short*)(ws + 54538240);      // 8192x3072 bf16
  unsigned short* aout  = (unsigned short*)(ws + 104869888);     // 8192x2048 bf16
  // total 138,424,320 bytes

  // fused prep: x convert + 4 weight transposes + bias concat
  prep_kernel<<<PB_ALL, 256, 0, stream>>>(x, Wq, Wk, Wv, Wo, bq, bk, bv,
                                          xb, WqkvT, WoT, bqkv);
  // fused QKV projection: (8192x2048) @ (2048x3072)^T-layout -> qkv bf16
  gemm_bt_kernel<true><<<dim3(24, 64), 256, 0, stream>>>(xb, WqkvT, qkv, bqkv,
                                                         MM, NQKV, DD, NQKV);
  // rmsnorm+rope on q,k  |  V transpose into the now-dead xb region
  norm_vtr_kernel<<<45056, 256, 0, stream>>>(qkv, qns, kns, vtb);
  // MFMA flash attention
  fattn_kernel<<<2048, 256, 0, stream>>>(qkv, vtb, aout);
  // output projection -> fp32 d_out
  gemm_bt_kernel<false><<<dim3(16, 64), 256, 0, stream>>>(aout, WoT, d_out, bo,
                                                          MM, DD, DD, DD);
  (void)in_sizes; (void)n_in; (void)out_size; (void)ws_size;
}

// Round 5
// 422.655 us; speedup vs baseline: 7.3155x; 1.0446x over previous
//
#include <hip/hip_runtime.h>
#include <stdint.h>

typedef __attribute__((ext_vector_type(4))) float floatx4;
typedef __attribute__((ext_vector_type(16))) float floatx16;
typedef __attribute__((ext_vector_type(8))) short short8;

// Problem constants
#define BB 16
#define SS 512
#define DD 2048
#define HH_ 16
#define HD 128
#define GG 4
#define MM (BB*SS)          // 8192
#define NQKV 3072           // 2048 q + 512 k + 512 v

__device__ __forceinline__ unsigned short f2bf(float f){
  unsigned u = __builtin_bit_cast(unsigned, f);
  u += 0x7fffu + ((u >> 16) & 1u);            // RNE
  return (unsigned short)(u >> 16);
}
__device__ __forceinline__ float bf2f_lo(unsigned d){
  return __builtin_bit_cast(float, d << 16);
}
__device__ __forceinline__ float bf2f_hi(unsigned d){
  return __builtin_bit_cast(float, d & 0xffff0000u);
}

// NOTE: LDS dest must be WAVE-UNIFORM; HW writes base + lane*16. Passing a
// lane-divergent pointer (R4) correlated with 1.26e7 bank conflicts.
__device__ __forceinline__ void async_copy16(const void* g, void* l){
  __builtin_amdgcn_global_load_lds((const __attribute__((address_space(1))) unsigned*)g,
                                   (__attribute__((address_space(3))) unsigned*)l,
                                   16, 0, 0);
}

// ---------------- fused prep: cvt_x | 4x transpose | bias concat ----------------
#define PB_CVT   16384
#define PB_TRQ   (PB_CVT + 4096)
#define PB_TRK   (PB_TRQ + 1024)
#define PB_TRV   (PB_TRK + 1024)
#define PB_TRO   (PB_TRV + 4096)
#define PB_ALL   (PB_TRO + 12)

__global__ __launch_bounds__(256) void prep_kernel(
    const float* __restrict__ x,
    const float* __restrict__ Wq, const float* __restrict__ Wk,
    const float* __restrict__ Wv, const float* __restrict__ Wo,
    const float* __restrict__ bq, const float* __restrict__ bk,
    const float* __restrict__ bv,
    unsigned short* __restrict__ xb, unsigned short* __restrict__ WqkvT,
    unsigned short* __restrict__ WoT, float* __restrict__ bqkv)
{
  __shared__ float tile[32][33];
  const int bid = blockIdx.x, tid = threadIdx.x;

  if (bid < PB_CVT) {                       // ---- x fp32 -> bf16 ----
    const int i = bid * 256 + tid;
    float4 f = ((const float4*)x)[i];
    ushort4 o;
    o.x = f2bf(f.x); o.y = f2bf(f.y); o.z = f2bf(f.z); o.w = f2bf(f.w);
    ((ushort4*)xb)[i] = o;
    return;
  }
  if (bid < PB_TRO) {                       // ---- W transpose+cvt ----
    const float* src; unsigned short* dst; int R, C, b2;
    if (bid < PB_TRQ)      { src = Wq; dst = WqkvT;                          R = 2048; C = 2048; b2 = bid - PB_CVT; }
    else if (bid < PB_TRK) { src = Wk; dst = WqkvT + (size_t)2048 * 2048;    R = 2048; C = 512;  b2 = bid - PB_TRQ; }
    else if (bid < PB_TRV) { src = Wv; dst = WqkvT + (size_t)2560 * 2048;    R = 2048; C = 512;  b2 = bid - PB_TRK; }
    else                   { src = Wo; dst = WoT;                            R = 2048; C = 2048; b2 = bid - PB_TRV; }
    const int nbx = C >> 5;
    const int c0 = (b2 % nbx) * 32, r0 = (b2 / nbx) * 32;
    const int tx = tid & 31, ty = tid >> 5;          // 32 x 8
    #pragma unroll
    for (int j = 0; j < 32; j += 8)
      tile[ty + j][tx] = src[(size_t)(r0 + ty + j) * C + (c0 + tx)];
    __syncthreads();
    #pragma unroll
    for (int j = 0; j < 32; j += 8)
      dst[(size_t)(c0 + ty + j) * R + (r0 + tx)] = f2bf(tile[tx][ty + j]);
    return;
  }
  {                                         // ---- bias concat ----
    const int i = (bid - PB_TRO) * 256 + tid;
    if (i < NQKV)
      bqkv[i] = (i < 2048) ? bq[i] : (i < 2560 ? bk[i - 2048] : bv[i - 2560]);
  }
}

// ---------------- bf16 GEMM: C = A(MxK) @ Bt(NxK)^T + bias ----------------
// 128x128 tile, BK=64, 32x32x16 MFMA (2x2 per wave), global_load_lds(16B).
// LDS rows = 64 ushorts = 8 x 16B granules; logical granule g of row r at
// physical slot g ^ (r&7). Swizzle applied by permuting which GLOBAL granule
// each lane fetches; LDS dest is wave-uniform (HW adds lane*16).
template<bool OUT_BF16>
__global__ __launch_bounds__(256) void gemm_bt_kernel(
    const unsigned short* __restrict__ A,
    const unsigned short* __restrict__ Bt,
    void* __restrict__ Cout,
    const float* __restrict__ bias,
    int M, int N, int K, int ldc)
{
  __shared__ unsigned short sA[128 * 64];   // 16 KB
  __shared__ unsigned short sB[128 * 64];   // 16 KB
  const int tid  = threadIdx.x;
  const int wave = tid >> 6;
  const int lane = tid & 63;
  const int m0 = blockIdx.y * 128;
  const int n0 = blockIdx.x * 128;
  const int wm = (wave >> 1) * 64;
  const int wn = (wave & 1) * 64;

  floatx16 acc[2][2];
  #pragma unroll
  for (int i = 0; i < 2; i++)
    #pragma unroll
    for (int j = 0; j < 2; j++)
      #pragma unroll
      for (int r = 0; r < 16; r++) acc[i][j][r] = 0.f;

  // staging: wave w fills rows [32w,32w+32), 4 calls x 8 rows; lane l -> row
  // 32w+8c+(l>>3), slot l&7, fetches logical granule (l&7)^((l>>3)&7)
  const int sglog = (lane & 7) ^ ((lane >> 3) & 7);
  const unsigned short* gA = A  + (size_t)(m0 + 32 * wave + (lane >> 3)) * K + sglog * 8;
  const unsigned short* gB = Bt + (size_t)(n0 + 32 * wave + (lane >> 3)) * K + sglog * 8;
  unsigned short* lA = &sA[32 * wave * 64];   // wave-uniform; HW adds lane*16B
  unsigned short* lB = &sB[32 * wave * 64];

  for (int k0 = 0; k0 < K; k0 += 64) {
    #pragma unroll
    for (int c = 0; c < 4; ++c) {
      async_copy16(gA + (size_t)c * 8 * K + k0, lA + c * 512);
      async_copy16(gB + (size_t)c * 8 * K + k0, lB + c * 512);
    }
    __syncthreads();

    #pragma unroll
    for (int kh = 0; kh < 4; ++kh) {
      const int slot = (kh * 2 + (lane >> 5)) ^ (lane & 7);
      short8 aF[2], bF[2];
      #pragma unroll
      for (int i = 0; i < 2; ++i)
        aF[i] = *(const short8*)(&sA[(wm + i * 32 + (lane & 31)) * 64 + slot * 8]);
      #pragma unroll
      for (int j = 0; j < 2; ++j)
        bF[j] = *(const short8*)(&sB[(wn + j * 32 + (lane & 31)) * 64 + slot * 8]);
      #pragma unroll
      for (int i = 0; i < 2; ++i)
        #pragma unroll
        for (int j = 0; j < 2; ++j)
          acc[i][j] = __builtin_amdgcn_mfma_f32_32x32x16_bf16(aF[i], bF[j], acc[i][j], 0, 0, 0);
    }
    __syncthreads();
  }

  // epilogue: 32x32 C/D layout col=lane&31, row=(reg&3)+8*(reg>>2)+4*(lane>>5)
  const int cc = lane & 31;
  const int rb = 4 * (lane >> 5);
  #pragma unroll
  for (int j = 0; j < 2; j++) {
    const int col = n0 + wn + j * 32 + cc;
    const float bval = bias[col];
    #pragma unroll
    for (int i = 0; i < 2; i++) {
      #pragma unroll
      for (int reg = 0; reg < 16; reg++) {
        const int row = m0 + wm + i * 32 + (reg & 3) + 8 * (reg >> 2) + rb;
        const float v = acc[i][j][reg] + bval;
        if (OUT_BF16)
          ((unsigned short*)Cout)[(size_t)row * ldc + col] = f2bf(v);
        else
          ((float*)Cout)[(size_t)row * ldc + col] = v;
      }
    }
  }
}

// ---------------- fused RMSNorm+RoPE (q,k) | V transpose ----------------
__global__ __launch_bounds__(256) void norm_vtr_kernel(
    unsigned short* __restrict__ qkv,
    const float* __restrict__ qs, const float* __restrict__ ks,
    unsigned short* __restrict__ vt)
{
  __shared__ unsigned short tileV[32][34];
  const int bid = blockIdx.x, tid = threadIdx.x;

  if (bid < 40960) {
    const int wave = tid >> 6, lane = tid & 63;
    const int gw  = bid * 4 + wave;
    const int row = gw / 20;
    const int hh  = gw % 20;          // 0..15 q heads, 16..19 k heads
    const bool isq = hh < 16;

    unsigned* p = (unsigned*)(qkv + (size_t)row * NQKV + hh * 128) + lane;
    unsigned d = *p;
    float x1 = bf2f_lo(d), x2 = bf2f_hi(d);

    float ss = x1 * x1 + x2 * x2;
    #pragma unroll
    for (int off = 32; off; off >>= 1) ss += __shfl_xor(ss, off, 64);
    const float r = rsqrtf(ss * (1.f / 128.f) + 1e-6f);

    const float2 sc = ((const float2*)(isq ? qs : ks))[lane];
    float n1 = x1 * r * sc.x;
    float n2 = x2 * r * sc.y;

    const float t = (float)(row & (SS - 1));
    const float freq = __expf((float)lane * (-2.f / 128.f) * 9.21034037197618f);
    float sn, cs;
    __sincosf(t * freq, &sn, &cs);
    float o1 = n1 * cs - n2 * sn;
    float o2 = n1 * sn + n2 * cs;
    if (isq) { o1 *= (1.f / 128.f); o2 *= (1.f / 128.f); }

    *p = (unsigned)f2bf(o1) | ((unsigned)f2bf(o2) << 16);
    return;
  }
  {
    const int b2 = bid - 40960;
    const int hd0 = (b2 & 3) * 32, t0 = ((b2 >> 2) & 15) * 32, bg = b2 >> 6;
    const int tx = tid & 31, ty = tid >> 5;
    const int b = bg >> 2, g = bg & 3;
    const unsigned short* src = qkv + (size_t)b * SS * NQKV + 2560 + g * HD;
    #pragma unroll
    for (int j = 0; j < 32; j += 8)
      tileV[ty + j][tx] = src[(size_t)(t0 + ty + j) * NQKV + hd0 + tx];
    __syncthreads();
    unsigned short* dst = vt + (size_t)bg * HD * SS;
    #pragma unroll
    for (int j = 0; j < 32; j += 8)
      dst[(size_t)(hd0 + ty + j) * SS + t0 + tx] = tileV[tx][ty + j];
  }
}

// ---------------- MFMA flash attention ----------------
// LDS exactly 40 KB -> 4 blocks/CU. sP uses XOR-granule swizzle (granule g of
// row r at slot g^(r&7)): reads conflict-free, writes 2-way (free).
__global__ __launch_bounds__(256, 4) void fattn_kernel(
    const unsigned short* __restrict__ qkv,
    const unsigned short* __restrict__ vtb,
    unsigned short* __restrict__ aout)
{
  __shared__ unsigned short sK[64 * 128];     // 16 KB
  __shared__ unsigned short sV[128 * 64];     // 16 KB
  __shared__ unsigned short sP[4][16 * 64];   //  8 KB

  const int lane = threadIdx.x & 63, wave = threadIdx.x >> 6;
  const int quad = lane >> 4, col = lane & 15;
  const int idx = blockIdx.x;
  const int qb = 7 - (idx >> 8);              // heavy (long-K) blocks first
  const int bh = idx & 255;
  const int b = bh >> 4, h = bh & 15, g = h >> 2;

  const int qrow = qb * 64 + wave * 16 + col;
  const unsigned short* qg = qkv + ((size_t)(b * SS + qrow)) * NQKV + h * HD + quad * 8;
  short8 qf[4];
  #pragma unroll
  for (int c = 0; c < 4; ++c) qf[c] = *(const short8*)(qg + c * 32);

  const unsigned short* kg = qkv + (size_t)b * SS * NQKV + 2048 + g * HD;
  const unsigned short* vg = vtb + ((size_t)(b * GG + g)) * HD * SS;

  floatx4 acc_o[8];
  #pragma unroll
  for (int i = 0; i < 8; ++i) acc_o[i] = (floatx4){0.f, 0.f, 0.f, 0.f};
  float m[4] = {-INFINITY, -INFINITY, -INFINITY, -INFINITY};
  float l[4] = {0.f, 0.f, 0.f, 0.f};

  for (int kt = 0; kt <= qb; ++kt) {
    const int t0 = kt * 64;
    #pragma unroll
    for (int c = 0; c < 4; ++c) {
      const int ci = c * 4 + wave;
      { const int r  = ci * 4 + (lane >> 4);
        const int gl = (lane & 15) ^ (r & 15);
        async_copy16(kg + (size_t)(t0 + r) * NQKV + gl * 8, &sK[ci * 512]); }
      { const int r  = ci * 8 + (lane >> 3);
        const int gl = (lane & 7) ^ (r & 7);
        async_copy16(vg + (size_t)r * SS + t0 + gl * 8, &sV[ci * 512]); }
    }
    __syncthreads();

    floatx4 sc[4];
    #pragma unroll
    for (int s = 0; s < 4; ++s) sc[s] = (floatx4){0.f, 0.f, 0.f, 0.f};
    #pragma unroll
    for (int s = 0; s < 4; ++s) {
      const int trow = s * 16 + col;
      #pragma unroll
      for (int c = 0; c < 4; ++c) {
        const int p = (c * 4 + quad) ^ (trow & 15);
        const short8 kf = *(const short8*)(&sK[trow * 128 + p * 8]);
        sc[s] = __builtin_amdgcn_mfma_f32_16x16x32_bf16(qf[c], kf, sc[s], 0, 0, 0);
      }
    }

    if (kt == qb) {
      #pragma unroll
      for (int s = 0; s < 4; ++s)
        #pragma unroll
        for (int r = 0; r < 4; ++r)
          if (s * 16 + col > wave * 16 + quad * 4 + r) sc[s][r] = -1e30f;
    }

    float mx[4], alpha[4], lsum[4];
    #pragma unroll
    for (int r = 0; r < 4; ++r) {
      mx[r] = fmaxf(fmaxf(sc[0][r], sc[1][r]), fmaxf(sc[2][r], sc[3][r]));
      #pragma unroll
      for (int off = 8; off; off >>= 1) mx[r] = fmaxf(mx[r], __shfl_xor(mx[r], off, 16));
      mx[r] = fmaxf(mx[r], m[r]);
      alpha[r] = __expf(m[r] - mx[r]);
      m[r] = mx[r];
      lsum[r] = 0.f;
    }
    // P write: row=quad*4+r, col_t=s*16+col; granule g=s*2+(col>>3), slot=g^(row&7)
    #pragma unroll
    for (int s = 0; s < 4; ++s)
      #pragma unroll
      for (int r = 0; r < 4; ++r) {
        const float p = __expf(sc[s][r] - m[r]);
        lsum[r] += p;
        const int row = quad * 4 + r;
        const int slot = (s * 2 + (col >> 3)) ^ (row & 7);
        sP[wave][row * 64 + slot * 8 + (col & 7)] = f2bf(p);
      }
    #pragma unroll
    for (int r = 0; r < 4; ++r) {
      #pragma unroll
      for (int off = 8; off; off >>= 1) lsum[r] += __shfl_xor(lsum[r], off, 16);
      l[r] = l[r] * alpha[r] + lsum[r];
    }
    #pragma unroll
    for (int n = 0; n < 8; ++n)
      #pragma unroll
      for (int r = 0; r < 4; ++r) acc_o[n][r] *= alpha[r];

    __asm__ volatile("s_waitcnt lgkmcnt(0)" ::: "memory");

    // P read (A-frag): m=col, k=kc*32+quad*8+j -> granule kc*4+quad, slot ^(m&7)
    short8 pf[2];
    #pragma unroll
    for (int kc = 0; kc < 2; ++kc)
      pf[kc] = *(const short8*)(&sP[wave][col * 64 + ((kc * 4 + quad) ^ (col & 7)) * 8]);
    #pragma unroll
    for (int n = 0; n < 8; ++n) {
      const int hdrow = n * 16 + col;
      #pragma unroll
      for (int kc = 0; kc < 2; ++kc) {
        const int p = (kc * 4 + quad) ^ (hdrow & 7);
        const short8 vf = *(const short8*)(&sV[hdrow * 64 + p * 8]);
        acc_o[n] = __builtin_amdgcn_mfma_f32_16x16x32_bf16(pf[kc], vf, acc_o[n], 0, 0, 0);
      }
    }
    __syncthreads();
  }

  float inv[4];
  #pragma unroll
  for (int r = 0; r < 4; ++r) inv[r] = 1.f / l[r];
  unsigned short* ob = aout + ((size_t)(b * SS + qb * 64 + wave * 16)) * DD + h * HD;
  #pragma unroll
  for (int n = 0; n < 8; ++n)
    #pragma unroll
    for (int r = 0; r < 4; ++r)
      ob[(size_t)(quad * 4 + r) * DD + n * 16 + col] = f2bf(acc_o[n][r] * inv[r]);
}

extern "C" void kernel_launch(void* const* d_in, const int* in_sizes, int n_in,
                              void* d_out, int out_size, void* d_ws, size_t ws_size,
                              hipStream_t stream) {
  const float* x   = (const float*)d_in[0];
  const float* Wq  = (const float*)d_in[1];
  const float* bq  = (const float*)d_in[2];
  const float* Wk  = (const float*)d_in[3];
  const float* bk  = (const float*)d_in[4];
  const float* Wv  = (const float*)d_in[5];
  const float* bv  = (const float*)d_in[6];
  const float* Wo  = (const float*)d_in[7];
  const float* bo  = (const float*)d_in[8];
  const float* qns = (const float*)d_in[9];
  const float* kns = (const float*)d_in[10];

  char* ws = (char*)d_ws;
  unsigned short* xb    = (unsigned short*)(ws);                 // 8192x2048 bf16 (dead after QKV gemm)
  unsigned short* vtb   = (unsigned short*)(ws);                 // 16x4x128x512 bf16 (reuses xb)
  unsigned short* WqkvT = (unsigned short*)(ws + 33554432);      // 3072x2048 bf16
  unsigned short* WoT   = (unsigned short*)(ws + 46137344);      // 2048x2048 bf16
  float*          bqkv  = (float*)         (ws + 54525952);      // 3072 f32
  unsigned short* qkv   = (unsigned short*)(ws + 54538240);      // 8192x3072 bf16
  unsigned short* aout  = (unsigned short*)(ws + 104869888);     // 8192x2048 bf16
  // total 138,424,320 bytes

  prep_kernel<<<PB_ALL, 256, 0, stream>>>(x, Wq, Wk, Wv, Wo, bq, bk, bv,
                                          xb, WqkvT, WoT, bqkv);
  gemm_bt_kernel<true><<<dim3(24, 64), 256, 0, stream>>>(xb, WqkvT, qkv, bqkv,
                                                         MM, NQKV, DD, NQKV);
  norm_vtr_kernel<<<45056, 256, 0, stream>>>(qkv, qns, kns, vtb);
  fattn_kernel<<<2048, 256, 0, stream>>>(qkv, vtb, aout);
  gemm_bt_kernel<false><<<dim3(16, 64), 256, 0, stream>>>(aout, WoT, d_out, bo,
                                                          MM, DD, DD, DD);
  (void)in_sizes; (void)n_in; (void)out_size; (void)ws_size;
}